// Round 8
// baseline (118.916 us; speedup 1.0000x reference)
//
#include <hip/hip_runtime.h>
#include <math.h>

#define NN 256
#define AA 20
#define UD 624
#define SS 768
#define NAU (AA*UD)          // 12480
#define PI_D 3.14159265358979323846

// ---------------- prep: dual-layout float4 transposes ------------------------
// blocks [0,256): pixA [i][j]; [256,512): pixB [j][i]
__global__ __launch_bounds__(256) void k_prep(const float* __restrict__ img,
                                              float4* __restrict__ pixA,
                                              float4* __restrict__ pixB) {
    const int blk = blockIdx.x;
    const int tid = threadIdx.x;
    if (blk < 256) {
        int idx = blk * 256 + tid;         // i*256+j
        float4 v;
        v.x = img[idx]; v.y = img[65536 + idx]; v.z = img[131072 + idx]; v.w = img[196608 + idx];
        pixA[idx] = v;
    } else {
        int oidx = (blk - 256) * 256 + tid; // j*256+i
        int j = oidx >> 8, i = oidx & 255;
        int idx = i * 256 + j;
        float4 v;
        v.x = img[idx]; v.y = img[65536 + idx]; v.z = img[131072 + idx]; v.w = img[196608 + idx];
        pixB[oidx] = v;
    }
}

// ---------------- forward: 4 rays/wave, 16-lane sample groups ----------------
__global__ __launch_bounds__(256) void k_fwd(const float4* __restrict__ pixA,
                                             const float4* __restrict__ pixB,
                                             const float* __restrict__ proj,
                                             float* __restrict__ g) {
    const int widx = threadIdx.x >> 6;
    const int lane = threadIdx.x & 63;
    const int qd = blockIdx.x * 4 + widx;   // quad id 0..3119
    const int a = qd / 156;                 // angle (uniform per wave)
    const int ub = (qd - a * 156) * 4;      // base detector of quad
    const int grp = lane >> 4;              // ray within quad
    const int sl = lane & 15;               // sample slot

    const float theta = (float)(((double)a + 0.5) * (2.0 * PI_D / (double)AA));
    float sn, cs;
    sincosf(theta, &sn, &cs);
    const float uc = (float)(-60.0 + ((double)(ub + grp) + 0.5) * (120.0 / 624.0));

    const float sx = 59.0f * cs, sy = 59.0f * sn;
    const float rx = -108.0f * cs - uc * sn;
    const float ry = -108.0f * sn + uc * cs;
    const float length = sqrtf(rx * rx + ry * ry);

    const float stepx = rx * (6.4f / 768.0f);
    const float basex = (sx + rx * (0.5f / 768.0f) + 20.0f) * 6.4f - 0.5f;
    const float stepy = ry * (6.4f / 768.0f);
    const float basey = (sy + ry * (0.5f / 768.0f) + 20.0f) * 6.4f - 0.5f;

    const bool useB = fabsf(stepx) > fabsf(stepy);
    const float4* __restrict__ im = useB ? pixB : pixA;
    const float bi = useB ? basex : basey;
    const float si = useB ? stepx : stepy;
    const float bo = useB ? basey : basex;
    const float so = useB ? stepy : stepx;

    float ax = 0.f, ay = 0.f, az = 0.f, aw = 0.f;

    for (int it = 0; it < 48; ++it) {
        const int s = (it << 4) + sl;
        float gi = fmaf((float)s, si, bi);
        float go = fmaf((float)s, so, bo);
        float fgi = floorf(gi), fgo = floorf(go);
        float fi = gi - fgi, fo = go - fgo;
        int i0 = (int)fgi, o0 = (int)fgo;
        int i1 = i0 + 1, o1 = o0 + 1;
        float wi0 = (i0 >= 0 && i0 < NN) ? (1.0f - fi) : 0.0f;
        float wi1 = (i1 >= 0 && i1 < NN) ? fi : 0.0f;
        float wo0 = (o0 >= 0 && o0 < NN) ? (1.0f - fo) : 0.0f;
        float wo1 = (o1 >= 0 && o1 < NN) ? fo : 0.0f;
        int ic0 = min(max(i0, 0), NN - 1), ic1 = min(max(i1, 0), NN - 1);
        int oc0 = min(max(o0, 0), NN - 1), oc1 = min(max(o1, 0), NN - 1);
        const float4 c00 = im[oc0 * NN + ic0];
        const float4 c10 = im[oc0 * NN + ic1];
        const float4 c01 = im[oc1 * NN + ic0];
        const float4 c11 = im[oc1 * NN + ic1];
        float w00 = wi0 * wo0, w10 = wi1 * wo0, w01 = wi0 * wo1, w11 = wi1 * wo1;
        ax += w00 * c00.x + w10 * c10.x + w01 * c01.x + w11 * c11.x;
        ay += w00 * c00.y + w10 * c10.y + w01 * c01.y + w11 * c11.y;
        az += w00 * c00.z + w10 * c10.z + w01 * c01.z + w11 * c11.z;
        aw += w00 * c00.w + w10 * c10.w + w01 * c01.w + w11 * c11.w;
    }

    for (int off = 8; off > 0; off >>= 1) {
        ax += __shfl_down(ax, off);
        ay += __shfl_down(ay, off);
        az += __shfl_down(az, off);
        aw += __shfl_down(aw, off);
    }

    if (sl == 0) {
        const int ray = a * UD + ub + grp;
        const float scale = length * (1.0f / 768.0f);
        const float wdet = 108.0f / sqrtf(108.0f * 108.0f + uc * uc);
        g[0 * NAU + ray] = (proj[0 * NAU + ray] - ax * scale) * wdet;
        g[1 * NAU + ray] = (proj[1 * NAU + ray] - ay * scale) * wdet;
        g[2 * NAU + ray] = (proj[2 * NAU + ray] - az * scale) * wdet;
        g[3 * NAU + ray] = (proj[3 * NAU + ray] - aw * scale) * wdet;
    }
}

// ---------------- conv: q[row,j] = sum_i g[row,i]*hh[|j-i|] ------------------
// 400 blocks: (row 0..79) x (jt 0..4, 128 outputs). hh built in-block via
// exact closed form; 4-output sliding window; 8-way t-split + LDS reduce.
__global__ __launch_bounds__(256) void k_conv(const float* __restrict__ g,
                                              float* __restrict__ q) {
    __shared__ float sgp[880];      // 128 zeros | 624 row | 128 zeros
    __shared__ float shh[624];
    __shared__ float sacc[1024];    // [seg 0..7][128]
    const int row = blockIdx.x / 5;      // b*AA + a
    const int jt  = blockIdx.x - row * 5;
    const int tid = threadIdx.x;

    // hh[n] closed form (exact value of sum_{k=1}^{1023} k(1+cos(pi k/1024))cos(pi k n/1024) / 2048^2)
    for (int n = tid; n < UD; n += 256) {
        double v;
        if (n == 0) {
            double s1 = sin(PI_D / 2048.0);
            v = 524288.0 - 0.5 / (s1 * s1);            // M^2/2 - inv(1)/2
        } else if (n == 1) {
            double s1 = sin(PI_D / 2048.0);
            v = 262144.0 - 0.5 / (s1 * s1);            // M^2/4 - inv(1)/2
        } else if (n & 1) {
            double s1 = sin(PI_D * (double)n / 2048.0);
            v = -0.5 / (s1 * s1);
        } else {
            double sa = sin(PI_D * (double)(n - 1) / 2048.0);
            double sb = sin(PI_D * (double)(n + 1) / 2048.0);
            v = -0.25 * (1.0 / (sa * sa) + 1.0 / (sb * sb));
        }
        shh[n] = (float)(v * (1.0 / 4194304.0));
    }
    for (int k = tid; k < 880; k += 256)
        sgp[k] = (k >= 128 && k < 128 + UD) ? g[row * UD + (k - 128)] : 0.0f;
    __syncthreads();

    const int quad = tid & 31;           // output quad within tile
    const int seg  = tid >> 5;           // 0..7 t-segment
    const int J0 = jt * 128;
    const int j0 = J0 + quad * 4;        // may exceed 623 only in last tile
    const int base = 128 + j0;

    const int n1 = min(J0 + 128, UD);    // minus: t in [0, n1)
    const int n2 = UD - 1 - J0;          // plus:  t in [1, 1+n2)

    float a0 = 0.f, a1 = 0.f, a2 = 0.f, a3 = 0.f;

    {   // minus segment: acc[k] += hh[t] * sgp[base + k - t]
        int ta = (n1 * seg) >> 3, tb = (n1 * (seg + 1)) >> 3;
        float w0 = sgp[base - ta],     w1 = sgp[base - ta + 1],
              w2 = sgp[base - ta + 2], w3 = sgp[base - ta + 3];
        for (int t = ta; t < tb; ++t) {
            float h = shh[t];
            a0 = fmaf(h, w0, a0); a1 = fmaf(h, w1, a1);
            a2 = fmaf(h, w2, a2); a3 = fmaf(h, w3, a3);
            float nv = sgp[base - t - 1];
            w3 = w2; w2 = w1; w1 = w0; w0 = nv;
        }
    }
    {   // plus segment: acc[k] += hh[t] * sgp[base + k + t]
        int ta = 1 + ((n2 * seg) >> 3), tb = 1 + ((n2 * (seg + 1)) >> 3);
        float w0 = sgp[base + ta],     w1 = sgp[base + ta + 1],
              w2 = sgp[base + ta + 2], w3 = sgp[base + ta + 3];
        for (int t = ta; t < tb; ++t) {
            float h = shh[t];
            a0 = fmaf(h, w0, a0); a1 = fmaf(h, w1, a1);
            a2 = fmaf(h, w2, a2); a3 = fmaf(h, w3, a3);
            float nv = sgp[base + t + 4];
            w0 = w1; w1 = w2; w2 = w3; w3 = nv;
        }
    }

    sacc[(seg << 7) + (quad << 2) + 0] = a0;
    sacc[(seg << 7) + (quad << 2) + 1] = a1;
    sacc[(seg << 7) + (quad << 2) + 2] = a2;
    sacc[(seg << 7) + (quad << 2) + 3] = a3;
    __syncthreads();
    if (tid < 128) {
        int j = J0 + tid;
        if (j < UD) {
            float s = sacc[tid] + sacc[128 + tid] + sacc[256 + tid] + sacc[384 + tid]
                    + sacc[512 + tid] + sacc[640 + tid] + sacc[768 + tid] + sacc[896 + tid];
            q[row * UD + j] = s;
        }
    }
}

// ---------------- back-projection: q batch-slab staged in LDS ----------------
__global__ __launch_bounds__(256) void k_bp(const float* __restrict__ q,
                                            float* __restrict__ out) {
    __shared__ float sq[AA * UD];       // 49920 B: this batch's filtered sino
    __shared__ float scs[AA], ssn[AA];
    const int tid = threadIdx.x;
    const int p = blockIdx.x * 256 + tid;   // 0..262143
    const int b = p >> 16;                  // constant per block

    const float4* __restrict__ qb4 = (const float4*)(q + b * AA * UD);
    float4* sq4 = (float4*)sq;
    for (int k = tid; k < AA * UD / 4; k += 256) sq4[k] = qb4[k];
    if (tid < AA) {
        float th = (float)(((double)tid + 0.5) * (2.0 * PI_D / (double)AA));
        float s, c;
        sincosf(th, &s, &c);
        scs[tid] = c;
        ssn[tid] = s;
    }
    __syncthreads();

    const int rem = p & 65535;
    const int i = rem >> 8;
    const int j = rem & 255;

    const float X = -20.0f + ((float)i + 0.5f) * 0.15625f;
    const float Y = -20.0f + ((float)j + 0.5f) * 0.15625f;

    const float uc0 = (float)(-60.0 + 0.5 * (120.0 / 624.0));
    const float duf = (float)(120.0 / 624.0);

    float acc = 0.0f;
#pragma unroll
    for (int a = 0; a < AA; ++a) {
        float cs = scs[a], sn = ssn[a];
        float t = 59.0f - (X * cs + Y * sn);
        float uu = 108.0f * (Y * cs - X * sn) / t;
        float k = (uu - uc0) / duf;
        float fk0 = floorf(k);
        float fk = k - fk0;
        int ik = (int)fk0;
        const float* qr = sq + a * UD;
        float v0 = ((unsigned)ik < (unsigned)UD) ? qr[ik] : 0.0f;
        float v1 = ((unsigned)(ik + 1) < (unsigned)UD) ? qr[ik + 1] : 0.0f;
        float val = v0 * (1.0f - fk) + v1 * fk;
        float w = 59.0f / t;
        acc += w * w * val;
    }
    out[p] = (0.5f * (float)(2.0 * PI_D / (double)AA)) * acc;
}

extern "C" void kernel_launch(void* const* d_in, const int* in_sizes, int n_in,
                              void* d_out, int out_size, void* d_ws, size_t ws_size,
                              hipStream_t stream) {
    const float* img  = (const float*)d_in[0];   // [4,256,256]
    const float* proj = (const float*)d_in[1];   // [4,20,624]
    float* out = (float*)d_out;                  // [4,256,256]

    char* ws = (char*)d_ws;
    float4* pixA = (float4*)ws;                              // 1 MiB
    float4* pixB = (float4*)(ws + (1 << 20));                // 1 MiB
    float*  g    = (float*)(ws + (2 << 20));                 // 199680 B (pad 200704)
    float*  q    = (float*)(ws + (2 << 20) + 200704);        // 199680 B

    k_prep<<<512,  256, 0, stream>>>(img, pixA, pixB);
    k_fwd <<<780,  256, 0, stream>>>(pixA, pixB, proj, g);
    k_conv<<<400,  256, 0, stream>>>(g, q);
    k_bp  <<<1024, 256, 0, stream>>>(q, out);
}